// Round 5
// baseline (1641.540 us; speedup 1.0000x reference)
//
#include <hip/hip_runtime.h>
#include <cstdint>
#include <cstddef>

// ---------------- constants ----------------
#define D_  384
#define H_  8
#define HS_ 48
#define L_  8
#define V_  32000
#define B_  32
#define T_  128
#define M_  4096   // B*T

typedef __bf16 bf16;
typedef __bf16 bf16x8 __attribute__((ext_vector_type(8)));
typedef float  floatx4 __attribute__((ext_vector_type(4)));

__device__ __forceinline__ unsigned short bfbits(float f) {
  union { bf16 b; unsigned short u; } cv; cv.b = (bf16)f; return cv.u;
}
__device__ __forceinline__ float bflo(unsigned u) {
  union { float f; unsigned x; } c; c.x = u << 16; return c.f;
}
__device__ __forceinline__ float bfhi(unsigned u) {
  union { float f; unsigned x; } c; c.x = u & 0xffff0000u; return c.f;
}

__device__ __forceinline__ float waveReduceSum(float v) {
  #pragma unroll
  for (int off = 32; off > 0; off >>= 1) v += __shfl_xor(v, off, 64);
  return v;
}

// async global->LDS, 16B per lane. LDS dest = wave-uniform base + lane*16.
__device__ __forceinline__ void gload_lds16(const void* g, void* l) {
  __builtin_amdgcn_global_load_lds(
      (const __attribute__((address_space(1))) void*)g,
      (__attribute__((address_space(3))) void*)l, 16, 0, 0);
}

// ---------------- embedding: x = tok_emb[idx] + pos_emb[t]; also bf16 copy ----------------
__global__ void embed_kernel(const int* __restrict__ idx, const float* __restrict__ tok,
                             const float* __restrict__ pos, float* __restrict__ x,
                             bf16* __restrict__ xb) {
  int e = blockIdx.x * 256 + threadIdx.x;       // 0 .. 4096*96-1
  int row = e / 96, c4 = (e % 96) * 4;
  int t = row & (T_ - 1);
  int tk = idx[row];
  const float4 tv = *(const float4*)(tok + (size_t)tk * D_ + c4);
  const float4 pv = *(const float4*)(pos + (size_t)t * D_ + c4);
  float4 o; o.x = tv.x + pv.x; o.y = tv.y + pv.y; o.z = tv.z + pv.z; o.w = tv.w + pv.w;
  *(float4*)(x + (size_t)row * D_ + c4) = o;
  uint2 u;
  u.x = (unsigned)bfbits(o.x) | ((unsigned)bfbits(o.y) << 16);
  u.y = (unsigned)bfbits(o.z) | ((unsigned)bfbits(o.w) << 16);
  *(uint2*)(xb + (size_t)row * D_ + c4) = u;
}

// ---------------- transpose+convert: W [K][N] f32 -> Wt [N][K] bf16 ----------------
__device__ __forceinline__ void transpose_tile(const float* __restrict__ src, bf16* __restrict__ dst,
                                               int K, int N, int k0, int n0) {
  __shared__ float tile[32][33];
  const int r = threadIdx.x >> 5, c = threadIdx.x & 31;
  #pragma unroll
  for (int i = 0; i < 4; i++)
    tile[r + 8*i][c] = src[(size_t)(k0 + r + 8*i) * N + n0 + c];
  __syncthreads();
  #pragma unroll
  for (int i = 0; i < 4; i++)
    dst[(size_t)(n0 + r + 8*i) * K + k0 + c] = (bf16)tile[c][r + 8*i];
}

// prologue: layer-0 weights. grid (48, 12, 3).
__global__ __launch_bounds__(256) void t_layer_kernel(
    const float* __restrict__ Wq, const float* __restrict__ Wk,
    const float* __restrict__ Wv, const float* __restrict__ Wo,
    const float* __restrict__ W1, const float* __restrict__ W2,
    bf16* __restrict__ wqkvoT, bf16* __restrict__ w1t, bf16* __restrict__ w2t) {
  if (blockIdx.z == 0) {
    const int mm = blockIdx.x / 12, nx = blockIdx.x % 12;   // which of QKVO, n-tile
    const float* src = mm == 0 ? Wq : mm == 1 ? Wk : mm == 2 ? Wv : Wo;
    transpose_tile(src, wqkvoT + (size_t)mm * (D_ * D_), D_, D_, blockIdx.y * 32, nx * 32);
  } else if (blockIdx.z == 1) {
    transpose_tile(W1, w1t, D_, 4 * D_, blockIdx.y * 32, blockIdx.x * 32);
  } else {
    transpose_tile(W2, w2t, 4 * D_, D_, blockIdx.x * 32, blockIdx.y * 32);
  }
}

__global__ __launch_bounds__(256) void t_head_kernel(const float* __restrict__ lmW, bf16* __restrict__ dst) {
  transpose_tile(lmW, dst, D_, V_, blockIdx.y * 32, blockIdx.x * 32);
}

// ---------------- GEMM: C[M][N] = A[M][K](bf16) @ Bt[N][K]^T(bf16), fp32 acc ----------------
// BMx128 block tile, 4 waves 2x2, BK=32, mfma_f32_16x16x32_bf16, 2-phase LDS dbuf,
// global_load_lds width=16, both-sides XOR swizzle (slot ^= (row>>1)&3).
template<int BM, bool BIAS, bool RESID, bool RELU, bool OUTBF>
__device__ __forceinline__ void gemm_core(
    const bf16* __restrict__ A, const bf16* __restrict__ Bt,
    const float* __restrict__ bias, const float* __restrict__ resid,
    void* __restrict__ Cout, int N, int K, int m0, int n0)
{
  constexpr int MTC = BM / 32;           // m-fragments per wave (4 or 2)
  __shared__ bf16 As[2][BM * 32];
  __shared__ bf16 Bs[2][128 * 32];
  const int tid  = threadIdx.x;
  const int lane = tid & 63;
  const int wave = tid >> 6;
  const int wr = wave >> 1, wc = wave & 1;
  const int lrow = lane & 15, quad = lane >> 4;
  const int rdoff = ((quad ^ ((lrow >> 1) & 3)) << 3);   // swizzled bf16 col within row

  const int srow = lane >> 2;
  const int scol = (((lane & 3) ^ ((lane >> 3) & 3)) << 3);

  floatx4 acc[MTC][4];
  #pragma unroll
  for (int i = 0; i < MTC; i++)
    #pragma unroll
    for (int j = 0; j < 4; j++) acc[i][j] = floatx4{0.f, 0.f, 0.f, 0.f};

  const bf16* gA = A  + (size_t)(m0 + wave * (BM / 4) + srow) * K + scol;
  const bf16* gB = Bt + (size_t)(n0 + wave * 32       + srow) * K + scol;

  auto STAGE = [&](int buf, int kk) {
    bf16* lA = &As[buf][wave * (BM * 8)];
    bf16* lB = &Bs[buf][wave * 1024];
    #pragma unroll
    for (int j = 0; j < BM / 64; j++)
      gload_lds16(gA + kk + (size_t)j * 16 * K, lA + j * 512);
    #pragma unroll
    for (int j = 0; j < 2; j++)
      gload_lds16(gB + kk + (size_t)j * 16 * K, lB + j * 512);
  };

  STAGE(0, 0);
  __syncthreads();
  int cur = 0;
  for (int k0 = 0; k0 < K; k0 += 32) {
    if (k0 + 32 < K) STAGE(cur ^ 1, k0 + 32);
    bf16x8 af[MTC], bfr[4];
    #pragma unroll
    for (int mt = 0; mt < MTC; mt++)
      af[mt]  = *(const bf16x8*)&As[cur][(wr * (BM / 2) + mt * 16 + lrow) * 32 + rdoff];
    #pragma unroll
    for (int nt = 0; nt < 4; nt++)
      bfr[nt] = *(const bf16x8*)&Bs[cur][(wc * 64 + nt * 16 + lrow) * 32 + rdoff];
    #pragma unroll
    for (int mt = 0; mt < MTC; mt++)
      #pragma unroll
      for (int nt = 0; nt < 4; nt++)
        acc[mt][nt] = __builtin_amdgcn_mfma_f32_16x16x32_bf16(af[mt], bfr[nt], acc[mt][nt], 0, 0, 0);
    __syncthreads();
    cur ^= 1;
  }

  #pragma unroll
  for (int mt = 0; mt < MTC; mt++) {
    #pragma unroll
    for (int nt = 0; nt < 4; nt++) {
      const int col = n0 + wc * 64 + nt * 16 + lrow;
      float bv = 0.f;
      if (BIAS) bv = bias[col];
      #pragma unroll
      for (int i = 0; i < 4; i++) {
        const int row = m0 + wr * (BM / 2) + mt * 16 + quad * 4 + i;
        float vv = acc[mt][nt][i] + bv;
        if (RESID) vv += resid[(size_t)row * N + col];
        if (RELU)  vv = vv > 0.f ? vv : 0.f;
        if (OUTBF) ((bf16*)Cout)[(size_t)row * N + col] = (bf16)vv;
        else       ((float*)Cout)[(size_t)row * N + col] = vv;
      }
    }
  }
}

template<int BM, bool BIAS, bool RESID, bool RELU, bool OUTBF>
__global__ __launch_bounds__(256) void gemm_kernel(const bf16* __restrict__ A, const bf16* __restrict__ Bt,
    const float* __restrict__ bias, const float* __restrict__ resid, void* __restrict__ C, int N, int K) {
  gemm_core<BM, BIAS, RESID, RELU, OUTBF>(A, Bt, bias, resid, C, N, K, blockIdx.x * BM, blockIdx.y * 128);
}

// q/k/v produced directly in bf16
__global__ __launch_bounds__(256) void gemm_qkv_kernel(const bf16* __restrict__ A, const bf16* __restrict__ Wt,
    bf16* __restrict__ q, bf16* __restrict__ k, bf16* __restrict__ v) {
  const bf16* Bt = Wt + (size_t)blockIdx.z * (D_ * D_);
  bf16* C = blockIdx.z == 0 ? q : (blockIdx.z == 1 ? k : v);
  gemm_core<128, false, false, false, true>(A, Bt, nullptr, nullptr, C, D_, D_, blockIdx.x * 128, blockIdx.y * 128);
}

// FFN1 fused with next layer's weight transposes. grid (48, 12, 4).
__global__ __launch_bounds__(256) void ffn1t_kernel(
    const bf16* __restrict__ A, const bf16* __restrict__ Bt, const float* __restrict__ bias,
    bf16* __restrict__ hb,
    const float* __restrict__ nWq, const float* __restrict__ nWk,
    const float* __restrict__ nWv, const float* __restrict__ nWo,
    const float* __restrict__ nW1, const float* __restrict__ nW2,
    bf16* __restrict__ nwqkvoT, bf16* __restrict__ nw1t, bf16* __restrict__ nw2t) {
  if (blockIdx.z == 0) {
    if (blockIdx.x >= 32) return;
    gemm_core<128, true, false, true, true>(A, Bt, bias, nullptr, hb, 4 * D_, D_,
                                            blockIdx.x * 128, blockIdx.y * 128);
  } else if (blockIdx.z == 1) {
    const int mm = blockIdx.x / 12, nx = blockIdx.x % 12;
    const float* src = mm == 0 ? nWq : mm == 1 ? nWk : mm == 2 ? nWv : nWo;
    transpose_tile(src, nwqkvoT + (size_t)mm * (D_ * D_), D_, D_, blockIdx.y * 32, nx * 32);
  } else if (blockIdx.z == 2) {
    transpose_tile(nW1, nw1t, D_, 4 * D_, blockIdx.y * 32, blockIdx.x * 32);
  } else {
    transpose_tile(nW2, nw2t, 4 * D_, D_, blockIdx.x * 32, blockIdx.y * 32);
  }
}

// ---------------- GEMM + residual + LayerNorm fused epilogue ----------------
// Tile 16 x 384 (full row), grid = M/16 = 256 blocks, 256 threads = 4 waves each
// owning a 96-col strip (6 n-frags). After K-loop: vv = acc + bias + resid; row
// stats via 16-lane shfl reduce + cross-wave LDS reduce; write x fp32 + xb bf16.
// Staging: 24 B-chunks (16 rows x 64B each) split 6-per-wave at compile time;
// wave 0 additionally stages the A tile.
__global__ __launch_bounds__(256) void gemm_ln_kernel(
    const bf16* __restrict__ A, const bf16* __restrict__ Bt,
    const float* __restrict__ bias, const float* __restrict__ g,
    const float* __restrict__ beta, float* __restrict__ x,   // resid in, post-LN out
    bf16* __restrict__ xb, int K)
{
  __shared__ bf16 As[2][16 * 32];
  __shared__ bf16 Bs[2][384 * 32];
  __shared__ float red[4][16][2];
  const int tid  = threadIdx.x;
  const int lane = tid & 63;
  const int wave = tid >> 6;
  const int lrow = lane & 15, quad = lane >> 4;
  const int m0 = blockIdx.x * 16;
  const int rdoff = ((quad ^ ((lrow >> 1) & 3)) << 3);
  const int srow = lane >> 2;
  const int scol = (((lane & 3) ^ ((lane >> 3) & 3)) << 3);

  floatx4 acc[6];
  #pragma unroll
  for (int j = 0; j < 6; j++) acc[j] = floatx4{0.f, 0.f, 0.f, 0.f};

  auto STAGE = [&](int buf, int kk) {
    #pragma unroll
    for (int i = 0; i < 6; i++) {
      const int c = wave * 6 + i;
      gload_lds16(Bt + (size_t)(c * 16 + srow) * K + kk + scol, &Bs[buf][c * 512]);
    }
    if (wave == 0)
      gload_lds16(A + (size_t)(m0 + srow) * K + kk + scol, &As[buf][0]);
  };

  STAGE(0, 0);
  __syncthreads();
  int cur = 0;
  for (int k0 = 0; k0 < K; k0 += 32) {
    if (k0 + 32 < K) STAGE(cur ^ 1, k0 + 32);
    const bf16x8 af = *(const bf16x8*)&As[cur][lrow * 32 + rdoff];
    bf16x8 bfr[6];
    #pragma unroll
    for (int nt = 0; nt < 6; nt++)
      bfr[nt] = *(const bf16x8*)&Bs[cur][(wave * 96 + nt * 16 + lrow) * 32 + rdoff];
    #pragma unroll
    for (int nt = 0; nt < 6; nt++)
      acc[nt] = __builtin_amdgcn_mfma_f32_16x16x32_bf16(af, bfr[nt], acc[nt], 0, 0, 0);
    __syncthreads();
    cur ^= 1;
  }

  // ---- epilogue: vv = acc + bias + resid; row stats; LN; write ----
  float sum[4] = {0.f, 0.f, 0.f, 0.f}, sq[4] = {0.f, 0.f, 0.f, 0.f};
  #pragma unroll
  for (int nt = 0; nt < 6; nt++) {
    const int col = wave * 96 + nt * 16 + lrow;
    const float bv = bias[col];
    #pragma unroll
    for (int i = 0; i < 4; i++) {
      const int row = m0 + quad * 4 + i;
      const float t = acc[nt][i] + bv + x[(size_t)row * D_ + col];
      acc[nt][i] = t;
      sum[i] += t; sq[i] += t * t;
    }
  }
  #pragma unroll
  for (int off = 1; off <= 8; off <<= 1) {
    #pragma unroll
    for (int i = 0; i < 4; i++) {
      sum[i] += __shfl_xor(sum[i], off, 64);
      sq[i]  += __shfl_xor(sq[i],  off, 64);
    }
  }
  if (lrow == 0) {
    #pragma unroll
    for (int i = 0; i < 4; i++) {
      red[wave][quad * 4 + i][0] = sum[i];
      red[wave][quad * 4 + i][1] = sq[i];
    }
  }
  __syncthreads();
  float mean[4], rs[4];
  #pragma unroll
  for (int i = 0; i < 4; i++) {
    const int rr = quad * 4 + i;
    const float S = red[0][rr][0] + red[1][rr][0] + red[2][rr][0] + red[3][rr][0];
    const float Q = red[0][rr][1] + red[1][rr][1] + red[2][rr][1] + red[3][rr][1];
    mean[i] = S * (1.f / 384.f);
    rs[i] = rsqrtf(Q * (1.f / 384.f) - mean[i] * mean[i] + 1e-5f);
  }
  #pragma unroll
  for (int nt = 0; nt < 6; nt++) {
    const int col = wave * 96 + nt * 16 + lrow;
    const float gv = g[col], bt = beta[col];
    #pragma unroll
    for (int i = 0; i < 4; i++) {
      const int row = m0 + quad * 4 + i;
      const float o = (acc[nt][i] - mean[i]) * rs[i] * gv + bt;
      x[(size_t)row * D_ + col]  = o;
      xb[(size_t)row * D_ + col] = (bf16)o;
    }
  }
}

// ---------------- attention: per (b,h), 4 threads per query row (12 dims each) ----------------
__global__ __launch_bounds__(512) void attn_kernel(const bf16* __restrict__ q,
    const bf16* __restrict__ k, const bf16* __restrict__ v, bf16* __restrict__ attnb) {
  __shared__ float ks[T_][48];
  __shared__ float vs[T_][48];
  const int bh = blockIdx.x;
  const int b = bh >> 3, h = bh & 7;
  const int r  = threadIdx.x >> 2;   // query row 0..127
  const int qq = threadIdx.x & 3;    // quarter of head dim
  const int o  = qq * 12;
  const size_t rowbase = ((size_t)(b * T_ + r)) * D_ + h * HS_ + o;
  float qr[12];
  #pragma unroll
  for (int j = 0; j < 3; j++) {
    const uint2 tk = *(const uint2*)(k + rowbase + 4*j);
    const uint2 tv = *(const uint2*)(v + rowbase + 4*j);
    const uint2 tq = *(const uint2*)(q + rowbase + 4*j);
    float4 fk, fv;
    fk.x = bflo(tk.x); fk.y = bfhi(tk.x); fk.z = bflo(tk.y); fk.w = bfhi(tk.y);
    fv.x = bflo(tv.x); fv.y = bfhi(tv.x); fv.z = bflo(tv.y); fv.w = bfhi(tv.y);
    *(float4*)&ks[r][o + 4*j] = fk;
    *(float4*)&vs[r][o + 4*j] = fv;
    qr[4*j]   = bflo(tq.x); qr[4*j+1] = bfhi(tq.x);
    qr[4*j+2] = bflo(tq.y); qr[4*j+3] = bfhi(tq.y);
  }
  __syncthreads();
  float m = -3.0e38f, l = 0.f, acc[12];
  #pragma unroll
  for (int j = 0; j < 12; j++) acc[j] = 0.f;
  const float scale = 0.14433756729740643f;   // 48^-0.5
  for (int c = 0; c < T_; c++) {
    float s = 0.f;
    #pragma unroll
    for (int j = 0; j < 12; j++) s += qr[j] * ks[c][o + j];
    s += __shfl_xor(s, 1, 64);
    s += __shfl_xor(s, 2, 64);
    s *= scale;
    if (c > r) s = -3.0e38f;                    // causal mask
    const float mn = fmaxf(m, s);
    const float al = __expf(m - mn);
    const float pp = __expf(s - mn);
    l = l * al + pp;
    #pragma unroll
    for (int j = 0; j < 12; j++) acc[j] = acc[j] * al + pp * vs[c][o + j];
    m = mn;
  }
  const float inv = 1.f / l;
  unsigned ob[6];
  #pragma unroll
  for (int j = 0; j < 6; j++)
    ob[j] = (unsigned)bfbits(acc[2*j] * inv) | ((unsigned)bfbits(acc[2*j+1] * inv) << 16);
  bf16* dst = attnb + rowbase;
  #pragma unroll
  for (int j = 0; j < 3; j++) {
    uint2 u; u.x = ob[2*j]; u.y = ob[2*j+1];
    *(uint2*)(dst + 4*j) = u;
  }
}

// ---------------- LayerNorm (final only): one wave per row ----------------
__global__ __launch_bounds__(256) void ln_kernel(const float* __restrict__ in,
    const float* __restrict__ g, const float* __restrict__ bta,
    float* __restrict__ xo, bf16* __restrict__ xbo) {
  const int wave = threadIdx.x >> 6, lane = threadIdx.x & 63;
  const int row = blockIdx.x * 4 + wave;
  const float* p = in + (size_t)row * D_;
  float v[6];
  #pragma unroll
  for (int j = 0; j < 6; j++) v[j] = p[lane + 64*j];
  float s = 0.f;
  #pragma unroll
  for (int j = 0; j < 6; j++) s += v[j];
  s = waveReduceSum(s);
  const float mean = s * (1.f / 384.f);
  float qv = 0.f;
  #pragma unroll
  for (int j = 0; j < 6; j++) { v[j] -= mean; qv += v[j] * v[j]; }
  qv = waveReduceSum(qv);
  const float rs = rsqrtf(qv * (1.f / 384.f) + 1e-5f);
  #pragma unroll
  for (int j = 0; j < 6; j++) {
    const int c = lane + 64*j;
    const float o = v[j] * rs * g[c] + bta[c];
    xo[(size_t)row * D_ + c]  = o;
    xbo[(size_t)row * D_ + c] = (bf16)o;
  }
}

// ---------------- driver ----------------
extern "C" void kernel_launch(void* const* d_in, const int* in_sizes, int n_in,
                              void* d_out, int out_size, void* d_ws, size_t ws_size,
                              hipStream_t stream) {
  const int*   index = (const int*)  d_in[0];
  const float* tok   = (const float*)d_in[1];
  const float* pos   = (const float*)d_in[2];
  const float* Wq    = (const float*)d_in[3];
  const float* Wk    = (const float*)d_in[4];
  const float* Wv    = (const float*)d_in[5];
  const float* Wo    = (const float*)d_in[6];
  const float* bo    = (const float*)d_in[7];
  const float* W1    = (const float*)d_in[8];
  const float* b1    = (const float*)d_in[9];
  const float* W2    = (const float*)d_in[10];
  const float* b2    = (const float*)d_in[11];
  const float* ln1g  = (const float*)d_in[12];
  const float* ln1b  = (const float*)d_in[13];
  const float* ln2g  = (const float*)d_in[14];
  const float* ln2b  = (const float*)d_in[15];
  const float* lnfg  = (const float*)d_in[16];
  const float* lnfb  = (const float*)d_in[17];
  const float* lmW   = (const float*)d_in[18];
  const float* lmb   = (const float*)d_in[19];
  float* out = (float*)d_out;
  char* ws = (char*)d_ws;

  // ws layout (48 MiB), tmp eliminated; double-buffered per-layer weights.
  float* x     = (float*)(ws + 0);          // 6.29 MB fp32 residual stream
  bf16*  xb    = (bf16*) (ws + 6291456);    // 3.15 MB bf16 copy of x
  bf16*  qb    = (bf16*) (ws + 9437184);    // 3.15 MB
  bf16*  kb    = (bf16*) (ws + 12582912);   // 3.15 MB
  bf16*  vb    = (bf16*) (ws + 15728640);   // 3.15 MB
  bf16*  attnb = (bf16*) (ws + 18874368);   // 3.15 MB
  bf16*  hb    = (bf16*) (ws + 22020096);   // 12.58 MB (ends 34603008)
  char*  wbuf0 = ws + 34603008;             // 3.54 MB: qkvoT(1.18) + w1t(1.18) + w2t(1.18)
  char*  wbuf1 = ws + 38141952;             // 3.54 MB (ends 41680896 < 48 MiB)
  bf16*  lmT   = (bf16*) (ws + 9437184);    // qb..hb span, dead at head time (24.58 MB fits 25.17)

  auto wq_of = [&](char* wb) { return (bf16*)wb; };
  auto w1_of = [&](char* wb) { return (bf16*)(wb + 1179648); };
  auto w2_of = [&](char* wb) { return (bf16*)(wb + 2359296); };

  embed_kernel<<<1536, 256, 0, stream>>>(index, tok, pos, x, xb);
  t_layer_kernel<<<dim3(48, 12, 3), 256, 0, stream>>>(
      Wq, Wk, Wv, Wo, W1, W2, wq_of(wbuf0), w1_of(wbuf0), w2_of(wbuf0));

  for (int l = 0; l < L_; l++) {
    char* wb  = (l & 1) ? wbuf1 : wbuf0;
    char* nwb = (l & 1) ? wbuf0 : wbuf1;
    gemm_qkv_kernel<<<dim3(32, 3, 3), 256, 0, stream>>>(xb, wq_of(wb), qb, kb, vb);
    attn_kernel<<<256, 512, 0, stream>>>(qb, kb, vb, attnb);
    // Wo + residual + LN1 fused
    gemm_ln_kernel<<<256, 256, 0, stream>>>(
        attnb, wq_of(wb) + 3 * D_ * D_, bo + l * D_, ln1g + l * D_, ln1b + l * D_, x, xb, D_);
    if (l < L_ - 1) {
      const size_t o1 = (size_t)(l + 1) * D_ * D_;
      const size_t o2 = (size_t)(l + 1) * D_ * 4 * D_;
      ffn1t_kernel<<<dim3(48, 12, 4), 256, 0, stream>>>(
          xb, w1_of(wb), b1 + l * 4 * D_, hb,
          Wq + o1, Wk + o1, Wv + o1, Wo + o1, W1 + o2, W2 + o2,
          wq_of(nwb), w1_of(nwb), w2_of(nwb));
    } else {
      gemm_kernel<128, true, false, true, true><<<dim3(32, 12), 256, 0, stream>>>(
          xb, w1_of(wb), b1 + l * 4 * D_, nullptr, hb, 4 * D_, D_);
    }
    // FFN2 + residual + LN2 fused
    gemm_ln_kernel<<<256, 256, 0, stream>>>(
        hb, w2_of(wb), b2 + l * D_, ln2g + l * D_, ln2b + l * D_, x, xb, 4 * D_);
  }
  ln_kernel<<<1024, 256, 0, stream>>>(x, lnfg, lnfb, x, xb);
  t_head_kernel<<<dim3(1000, 12), 256, 0, stream>>>(lmW, lmT);
  gemm_kernel<128, true, false, false, false><<<dim3(32, 250), 256, 0, stream>>>(
      xb, lmT, lmb, nullptr, out, V_, D_);
}